// Round 7
// baseline (392.345 us; speedup 1.0000x reference)
//
#include <hip/hip_runtime.h>
#include <stdint.h>

#define Bb   2
#define Tt   2048
#define Cc_  2048
#define Hh   16
#define Dd   128
#define Mm_  4096            // B*T
#define N1   6144            // 3*C
#define EPSf 1.1920929e-07f
#define SCALE (1.0f/128.0f)  // reference uses 1/D, not 1/sqrt(D)

typedef __bf16 bf16;
typedef __attribute__((ext_vector_type(8))) __bf16 bf16x8;
typedef __attribute__((ext_vector_type(4))) __bf16 bf16x4;
typedef __attribute__((ext_vector_type(4))) float  f32x4;

// ---- async global->LDS, width 16. LDS dest = wave-uniform base + lane*16.
__device__ __forceinline__ void gl_lds16(const bf16* g, bf16* l) {
  __builtin_amdgcn_global_load_lds(
      (const __attribute__((address_space(1))) unsigned int*)g,
      (__attribute__((address_space(3))) unsigned int*)l, 16, 0, 0);
}

// ------------------------------------------------------------------ cvt x->bf16
__global__ __launch_bounds__(256) void cvt_bf16(const float* __restrict__ in,
                                                bf16* __restrict__ out, int n) {
  int i = (blockIdx.x * 256 + threadIdx.x) * 4;
  if (i >= n) return;
  float4 v = *(const float4*)(in + i);
  union { bf16 h[4]; uint2 u; } o;
  o.h[0] = (bf16)v.x; o.h[1] = (bf16)v.y; o.h[2] = (bf16)v.z; o.h[3] = (bf16)v.w;
  *(uint2*)(out + i) = o.u;
}

// ------------------------------------------------------ RoPE cos/sin table
__global__ __launch_bounds__(256) void rope_tab(float2* __restrict__ rope) {
  int i = blockIdx.x * 256 + threadIdx.x;   // < 2048*64
  int t = i >> 6, d = i & 63;
  float ang = (float)t * exp2f((float)d * (-19.9315685693241740f / 64.0f));
  float sn, cs;
  sincosf(ang, &sn, &cs);
  rope[i] = make_float2(cs, sn);
}

// -------------------------------------------- transpose+convert: [R][Cc]f32 -> [Cc][R]bf16
// v2: float4 global loads (4x fewer load instrs); scalar LDS writes keep the
// 65-pad (reads conflict-free: bank = (lane + cc) % 32).
__global__ __launch_bounds__(256) void transpose_cvt(const float* __restrict__ in,
                                                     bf16* __restrict__ out,
                                                     int R, int Cc) {
  __shared__ float tile[64][65];
  int c0 = blockIdx.x * 64, r0 = blockIdx.y * 64;
  int tid = threadIdx.x;
#pragma unroll
  for (int j = 0; j < 4; ++j) {
    int idx = (j * 256 + tid) * 4;
    int r = idx >> 6, c = idx & 63;
    float4 v = *(const float4*)(in + (size_t)(r0 + r) * Cc + c0 + c);
    tile[r][c] = v.x; tile[r][c + 1] = v.y; tile[r][c + 2] = v.z; tile[r][c + 3] = v.w;
  }
  __syncthreads();
#pragma unroll
  for (int j = 0; j < 16; ++j) {
    int idx = tid + j * 256;
    int rr = idx & 63, cc = idx >> 6;
    out[(size_t)(c0 + cc) * R + r0 + rr] = (bf16)tile[rr][cc];
  }
}

// ------------------------------------------------------------------ fused QKV GEMM
// (unchanged from round 6 — epilogue v2, table RoPE, vector LDS)
__global__ __launch_bounds__(256) void gemm_qkv_fused(
    const bf16* __restrict__ A, const bf16* __restrict__ Bt,
    const float* __restrict__ qw, const float* __restrict__ kw,
    const float2* __restrict__ rope,
    bf16* __restrict__ Qg, bf16* __restrict__ Kg, bf16* __restrict__ VgT) {
  __shared__ __align__(16) bf16 smem[128 * 136];
  bf16* As = smem;
  bf16* Bs = smem + 128 * 64;
  const int Kk = Cc_;
  const int tid = threadIdx.x;
  const int wave = tid >> 6, lane = tid & 63;
  const int quad = lane >> 4, li = lane & 15;
  const int wm = wave >> 1, wn = wave & 1;
  const int m0 = blockIdx.y * 128, n0 = blockIdx.x * 128;

  f32x4 acc[4][4] = {};

  for (int kt = 0; kt < Kk; kt += 64) {
    __syncthreads();
#pragma unroll
    for (int j = 0; j < 4; ++j) {
      int c = j * 256 + tid;
      int r = c >> 3, cc = c & 7;
      int gc = ((cc ^ (r & 7)) << 3);
      gl_lds16(A + (size_t)(m0 + r) * Kk + kt + gc, &As[c * 8]);
      gl_lds16(Bt + (size_t)(n0 + r) * Kk + kt + gc, &Bs[c * 8]);
    }
    __syncthreads();
#pragma unroll
    for (int kc = 0; kc < 2; ++kc) {
      bf16x8 af[4], bfr[4];
#pragma unroll
      for (int t = 0; t < 4; ++t) {
        int rowa = wm * 64 + t * 16 + li;
        af[t] = *(const bf16x8*)&As[rowa * 64 + (((kc * 4 + quad) ^ (rowa & 7)) << 3)];
        int rowb = wn * 64 + t * 16 + li;
        bfr[t] = *(const bf16x8*)&Bs[rowb * 64 + (((kc * 4 + quad) ^ (rowb & 7)) << 3)];
      }
#pragma unroll
      for (int mi = 0; mi < 4; ++mi)
#pragma unroll
        for (int ni = 0; ni < 4; ++ni)
          acc[mi][ni] = __builtin_amdgcn_mfma_f32_16x16x32_bf16(af[mi], bfr[ni],
                                                                acc[mi][ni], 0, 0, 0);
    }
  }

  __syncthreads();
  const int s = blockIdx.x;
  const int b = m0 >> 11;
  const int tloc = m0 & 2047;
  bf16 (*tile)[136] = (bf16(*)[136])smem;

  if (s < 32) {
#pragma unroll
    for (int mi = 0; mi < 4; ++mi) {
      int row = wm * 64 + mi * 16 + quad * 4;
#pragma unroll
      for (int ni = 0; ni < 4; ++ni) {
        int col = wn * 64 + ni * 16 + li;
#pragma unroll
        for (int r = 0; r < 4; ++r)
          tile[row + r][col] = (bf16)acc[mi][ni][r];
      }
    }
    __syncthreads();

    const float* w = (s < 16) ? qw : kw;
    bf16* Og = (s < 16) ? Qg : Kg;
    const int h = s & 15;
    const size_t hb = (size_t)(b * Hh + h) * Tt;
    float w1[4], w2[4];
#pragma unroll
    for (int j = 0; j < 4; ++j) { w1[j] = w[li * 4 + j]; w2[j] = w[64 + li * 4 + j]; }
#pragma unroll
    for (int it = 0; it < 8; ++it) {
      int row = wave * 32 + it * 4 + quad;
      int t = tloc + row;
      bf16x4 x1 = *(const bf16x4*)&tile[row][li * 4];
      bf16x4 x2 = *(const bf16x4*)&tile[row][64 + li * 4];
      float f1[4], f2[4];
      float ss = 0.f;
#pragma unroll
      for (int j = 0; j < 4; ++j) {
        f1[j] = (float)x1[j]; f2[j] = (float)x2[j];
        ss += f1[j] * f1[j] + f2[j] * f2[j];
      }
#pragma unroll
      for (int o = 1; o < 16; o <<= 1) ss += __shfl_xor(ss, o);
      float rn = rsqrtf(ss * (1.0f / 128.0f) + EPSf);
      const float4* rp = (const float4*)(rope + t * 64 + li * 4);
      float4 ra = rp[0], rb = rp[1];
      float cs[4] = {ra.x, ra.z, rb.x, rb.z};
      float sn[4] = {ra.y, ra.w, rb.y, rb.w};
      bf16x4 o1, o2;
#pragma unroll
      for (int j = 0; j < 4; ++j) {
        float a1 = f1[j] * rn * w1[j], a2 = f2[j] * rn * w2[j];
        o1[j] = (bf16)(a1 * cs[j] - a2 * sn[j]);
        o2[j] = (bf16)(a2 * cs[j] + a1 * sn[j]);
      }
      size_t ob = (hb + t) * Dd + li * 4;
      *(bf16x4*)(Og + ob)      = o1;
      *(bf16x4*)(Og + ob + 64) = o2;
    }
  } else {
#pragma unroll
    for (int mi = 0; mi < 4; ++mi) {
      int row = wm * 64 + mi * 16 + quad * 4;
#pragma unroll
      for (int ni = 0; ni < 4; ++ni) {
        int col = wn * 64 + ni * 16 + li;
#pragma unroll
        for (int r = 0; r < 4; ++r)
          tile[col][row + r] = (bf16)acc[mi][ni][r];
      }
    }
    __syncthreads();
    const int h = s - 32;
    const size_t hb = (size_t)(b * Hh + h) * Dd;
#pragma unroll
    for (int it = 0; it < 8; ++it) {
      int d  = it * 16 + (tid >> 4);
      int t0 = (tid & 15) * 8;
      bf16x8 v = *(const bf16x8*)&tile[d][t0];
      *(bf16x8*)(VgT + (hb + d) * Tt + tloc + t0) = v;
    }
  }
}

// ------------------------------------------------------------------ GEMM 256x128, 8-wave
// (round-4 schedule; proj GEMM: 16x16 = 256 wg = 1 clean round)
template <typename OutT>
__global__ __launch_bounds__(512, 2) void gemm256(const bf16* __restrict__ A,
                                                  const bf16* __restrict__ Bt,
                                                  OutT* __restrict__ Cm,
                                                  int Nn, int Kk) {
  __shared__ __align__(16) bf16 As[2][256 * 64];
  __shared__ __align__(16) bf16 Bs[2][128 * 64];
  const int tid = threadIdx.x;
  const int wave = tid >> 6, lane = tid & 63;
  const int quad = lane >> 4, li = lane & 15;
  const int wm = wave >> 2, wn = wave & 3;

  const int nwg = gridDim.x * gridDim.y;
  const int wg  = blockIdx.y * gridDim.x + blockIdx.x;
  const int swz = (wg & 7) * (nwg >> 3) + (wg >> 3);
  const int m0 = (swz / gridDim.x) * 256;
  const int n0 = (swz % gridDim.x) * 128;

  const int NT = Kk >> 6;
  const int lrow = lane >> 3;
  const int lchk = (lane & 7) ^ lrow;

  auto stageA = [&](int tt, int h, int cb) {
    int kt = (tt < NT ? tt : NT - 1) << 6;
#pragma unroll
    for (int j = 0; j < 2; ++j) {
      int seg = j * 8 + wave;
      int r0 = ((seg >> 3) << 7) + (h << 6) + ((seg & 7) << 3);
      gl_lds16(A + (size_t)(m0 + r0 + lrow) * Kk + kt + (lchk << 3),
               &As[cb][r0 * 64]);
    }
  };
  auto stageB = [&](int tt, int cb) {
    int kt = (tt < NT ? tt : NT - 1) << 6;
#pragma unroll
    for (int j = 0; j < 2; ++j) {
      int seg = j * 8 + wave;
      int r0 = seg << 3;
      gl_lds16(Bt + (size_t)(n0 + r0 + lrow) * Kk + kt + (lchk << 3),
               &Bs[cb][r0 * 64]);
    }
  };

  f32x4 acc[8][2] = {};
  bf16x8 afr[4][2], bfr[2][2];

  auto rdA = [&](int h, int cb) {
#pragma unroll
    for (int mi = 0; mi < 4; ++mi) {
      int r = wm * 128 + h * 64 + mi * 16 + li;
#pragma unroll
      for (int kc = 0; kc < 2; ++kc)
        afr[mi][kc] = *(const bf16x8*)&As[cb][r * 64 + (((kc * 4 + quad) ^ (r & 7)) << 3)];
    }
  };
  auto rdB = [&](int cb) {
#pragma unroll
    for (int nj = 0; nj < 2; ++nj) {
      int r = wn * 32 + nj * 16 + li;
#pragma unroll
      for (int kc = 0; kc < 2; ++kc)
        bfr[nj][kc] = *(const bf16x8*)&Bs[cb][r * 64 + (((kc * 4 + quad) ^ (r & 7)) << 3)];
    }
  };
  auto mmac = [&](int mo) {
    __builtin_amdgcn_s_setprio(1);
#pragma unroll
    for (int kc = 0; kc < 2; ++kc)
#pragma unroll
      for (int mi = 0; mi < 4; ++mi)
#pragma unroll
        for (int nj = 0; nj < 2; ++nj)
          acc[mo + mi][nj] = __builtin_amdgcn_mfma_f32_16x16x32_bf16(
              afr[mi][kc], bfr[nj][kc], acc[mo + mi][nj], 0, 0, 0);
    __builtin_amdgcn_s_setprio(0);
  };

  auto tile = [&](int t, int cur, int nxt) {
    rdA(0, cur); rdB(cur);
    stageA(t + 1, 1, nxt);
    asm volatile("s_waitcnt lgkmcnt(8)" ::: "memory");
    __builtin_amdgcn_s_barrier();
    asm volatile("s_waitcnt lgkmcnt(0)" ::: "memory");
    __builtin_amdgcn_sched_barrier(0);
    mmac(0);
    asm volatile("s_waitcnt vmcnt(6)" ::: "memory");
    __builtin_amdgcn_s_barrier();
    rdA(1, cur);
    stageA(t + 2, 0, cur);
    stageB(t + 2, cur);
    __builtin_amdgcn_s_barrier();
    asm volatile("s_waitcnt lgkmcnt(0)" ::: "memory");
    __builtin_amdgcn_sched_barrier(0);
    mmac(4);
    asm volatile("s_waitcnt vmcnt(6)" ::: "memory");
    __builtin_amdgcn_s_barrier();
  };

  stageA(0, 0, 0); stageB(0, 0); stageA(0, 1, 0);
  stageA(1, 0, 1); stageB(1, 1);
  asm volatile("s_waitcnt vmcnt(6)" ::: "memory");
  __builtin_amdgcn_s_barrier();

  for (int t = 0; t < NT; t += 2) {
    tile(t, 0, 1);
    tile(t + 1, 1, 0);
  }
  asm volatile("s_waitcnt vmcnt(0)" ::: "memory");

#pragma unroll
  for (int mi = 0; mi < 8; ++mi) {
    int row = m0 + wm * 128 + mi * 16 + quad * 4;
#pragma unroll
    for (int nj = 0; nj < 2; ++nj) {
      int col = n0 + wn * 32 + nj * 16 + li;
#pragma unroll
      for (int r = 0; r < 4; ++r)
        Cm[(size_t)(row + r) * Nn + col] = (OutT)acc[mi][nj][r];
    }
  }
}

// ------------------------------------------------------------------ attention
// v2: SWAPPED QK^T (mfma(K,Q)) -> each lane holds 16 scores for ONE query
// (key = nt*16+quad*4+r, query = wave*16+li). Softmax/L lane-local; P goes to
// PV's A-fragment via in-register pack + 16 __shfl (ds_bpermute) + selects:
//   target (quad,li) pf[kc][e] = p[2kc+(quad>>1)][e&3] of lane (2(quad&1)+(e>>2))*16+li.
// Pl LDS buffer DELETED -> 32 KB -> 4 blocks/CU (launch_bounds(256,4)).
// T14 async staging (K reg-staged, V gl_lds) unchanged. setprio on MFMA clusters.
__global__ __launch_bounds__(256, 4) void attn(const bf16* __restrict__ Qg,
                                               const bf16* __restrict__ Kg,
                                               const bf16* __restrict__ VgT,
                                               bf16* __restrict__ Yg) {
  __shared__ __align__(16) bf16 Kl[64 * 128];
  __shared__ __align__(16) bf16 Vl[128 * 64];
  const int bh = blockIdx.x;
  const int qt = (int)gridDim.y - 1 - (int)blockIdx.y;  // long blocks first
  const int b = bh >> 4, h = bh & 15;
  const int tid = threadIdx.x, wave = tid >> 6, lane = tid & 63;
  const int quad = lane >> 4, li = lane & 15;
  const int q0 = qt * 64;

  const bf16* Qbase = Qg + ((size_t)bh * Tt + q0 + wave * 16 + li) * Dd;
  bf16x8 qf[4];
#pragma unroll
  for (int kc = 0; kc < 4; ++kc) qf[kc] = *(const bf16x8*)(Qbase + kc * 32 + quad * 8);

  f32x4 o[8] = {};
  float Lq = 0.f;                       // per-lane: partial L of query wave*16+li
  const int s0lane = ((quad & 1) << 5) + li;   // source lane for e0..3
  const int s1lane = s0lane + 16;              // source lane for e4..7
  const bool hi = (quad >> 1) != 0;            // selects nt_s = 2kc+1

  bf16x8 kreg[4];
  auto loadK = [&](int k0) {
#pragma unroll
    for (int j = 0; j < 4; ++j) {
      int c = j * 256 + tid;
      int r = c >> 4, cc = c & 15;
      kreg[j] = *(const bf16x8*)(Kg + ((size_t)bh * Tt + k0 + r) * Dd + ((cc ^ (r & 7)) << 3));
    }
  };
  auto stageV = [&](int k0) {
#pragma unroll
    for (int j = 0; j < 4; ++j) {
      int c = j * 256 + tid;
      int r = c >> 3, cc = c & 7;
      gl_lds16(VgT + ((size_t)bh * Dd + r) * Tt + k0 + ((cc ^ (r & 7)) << 3), &Vl[c * 8]);
    }
  };

  loadK(0);       // 4 vmem
  stageV(0);      // 4 vmem

  for (int kt = 0; kt <= qt; ++kt) {
    // ---- K regs ready (drain K(kt); V(kt)'s 4 remain in flight)
    asm volatile("s_waitcnt vmcnt(4)" ::: "memory");
#pragma unroll
    for (int j = 0; j < 4; ++j) {
      int c = j * 256 + tid;
      *(bf16x8*)&Kl[c * 8] = kreg[j];
    }
    if (kt < qt) loadK(kt * 64 + 64);            // prefetch next K
    asm volatile("s_waitcnt lgkmcnt(0)" ::: "memory");
    __builtin_amdgcn_s_barrier();                // Kl visible to all waves
    __builtin_amdgcn_sched_barrier(0);

    // ---- QK^T (SWAPPED: A=K, B=Q). s4[nt][r] = S[key nt*16+quad*4+r][query li]
    f32x4 s4[4] = {};
    __builtin_amdgcn_s_setprio(1);
#pragma unroll
    for (int nt = 0; nt < 4; ++nt) {
      int key = nt * 16 + li;
#pragma unroll
      for (int kc = 0; kc < 4; ++kc) {
        bf16x8 kf = *(const bf16x8*)&Kl[key * 128 + (((kc * 4 + quad) ^ (key & 7)) << 3)];
        s4[nt] = __builtin_amdgcn_mfma_f32_16x16x32_bf16(kf, qf[kc], s4[nt], 0, 0, 0);
      }
    }
    __builtin_amdgcn_s_setprio(0);

    // ---- exp + mask + L (lane-local), pack to bf16 pairs
    const bool diag = (kt == qt);
    uint32_t pk[4][2];
#pragma unroll
    for (int nt = 0; nt < 4; ++nt) {
      float e[4];
#pragma unroll
      for (int r = 0; r < 4; ++r) {
        e[r] = __expf(s4[nt][r] * SCALE);
        if (diag && (nt * 16 + quad * 4 + r > wave * 16 + li)) e[r] = 0.f;
        Lq += e[r];
      }
      union { bf16 hh[2]; uint32_t u; } c0_, c1_;
      c0_.hh[0] = (bf16)e[0]; c0_.hh[1] = (bf16)e[1]; pk[nt][0] = c0_.u;
      c1_.hh[0] = (bf16)e[2]; c1_.hh[1] = (bf16)e[3]; pk[nt][1] = c1_.u;
    }
    // ---- redistribute P -> A-fragments (16 shfl + selects, no LDS)
    bf16x8 pf[2];
#pragma unroll
    for (int kc = 0; kc < 2; ++kc) {
      union { uint32_t u[4]; bf16x8 v; } pu;
      uint32_t a, bsel;
      a = __shfl(pk[2 * kc][0], s0lane); bsel = __shfl(pk[2 * kc + 1][0], s0lane);
      pu.u[0] = hi ? bsel : a;
      a = __shfl(pk[2 * kc][1], s0lane); bsel = __shfl(pk[2 * kc + 1][1], s0lane);
      pu.u[1] = hi ? bsel : a;
      a = __shfl(pk[2 * kc][0], s1lane); bsel = __shfl(pk[2 * kc + 1][0], s1lane);
      pu.u[2] = hi ? bsel : a;
      a = __shfl(pk[2 * kc][1], s1lane); bsel = __shfl(pk[2 * kc + 1][1], s1lane);
      pu.u[3] = hi ? bsel : a;
      pf[kc] = pu.v;
    }

    // ---- V resident (drain V(kt); K(kt+1) prefetch stays in flight)
    if (kt < qt) { asm volatile("s_waitcnt vmcnt(4)" ::: "memory"); }
    else         { asm volatile("s_waitcnt vmcnt(0)" ::: "memory"); }
    __builtin_amdgcn_s_barrier();                // Vl visible; QK^T reads done
    __builtin_amdgcn_sched_barrier(0);

    // ---- PV: o[16 q][128 d] += P[16][64] * V[64][128]
    __builtin_amdgcn_s_setprio(1);
#pragma unroll
    for (int kc = 0; kc < 2; ++kc) {
#pragma unroll
      for (int u = 0; u < 8; ++u) {
        bf16x8 vf = *(const bf16x8*)&Vl[(u * 16 + li) * 64 + (((kc * 4 + quad) ^ (li & 7)) << 3)];
        o[u] = __builtin_amdgcn_mfma_f32_16x16x32_bf16(pf[kc], vf, o[u], 0, 0, 0);
      }
    }
    __builtin_amdgcn_s_setprio(0);
    asm volatile("" ::: "memory");               // pin PV ds_reads above barrier
    __builtin_amdgcn_s_barrier();                // all waves done with Vl
    __builtin_amdgcn_sched_barrier(0);
    if (kt < qt) stageV(kt * 64 + 64);           // prefetch next V into freed Vl
  }

  // final: cross-quad L sum, per-row inv via shfl, normalize + write
  Lq += __shfl_xor(Lq, 16);
  Lq += __shfl_xor(Lq, 32);
  float invq = 1.0f / Lq;
  float inv[4];
#pragma unroll
  for (int r = 0; r < 4; ++r) inv[r] = __shfl(invq, quad * 4 + r);
  int trow = q0 + wave * 16 + quad * 4;
#pragma unroll
  for (int u = 0; u < 8; ++u) {
    int col = h * Dd + u * 16 + li;
#pragma unroll
    for (int r = 0; r < 4; ++r)
      Yg[(size_t)(b * Tt + trow + r) * Cc_ + col] = (bf16)(o[u][r] * inv[r]);
  }
}

// ------------------------------------------------------------------ launch
extern "C" void kernel_launch(void* const* d_in, const int* in_sizes, int n_in,
                              void* d_out, int out_size, void* d_ws, size_t ws_size,
                              hipStream_t stream) {
  const float* x      = (const float*)d_in[0];
  const float* w_qkv  = (const float*)d_in[1];
  const float* w_proj = (const float*)d_in[2];
  const float* qnw    = (const float*)d_in[3];
  const float* knw    = (const float*)d_in[4];
  float* out = (float*)d_out;

  // workspace partition (bf16 elements)
  bf16* xb     = (bf16*)d_ws;                   // dead after fused qkv GEMM
  bf16* wqkvT  = xb + (size_t)Mm_ * Cc_;
  bf16* wprojT = wqkvT + (size_t)N1 * Cc_;
  bf16* Qg     = wprojT + (size_t)Cc_ * Cc_;
  bf16* Kg     = Qg + (size_t)Bb * Hh * Tt * Dd;
  bf16* VgT    = Kg + (size_t)Bb * Hh * Tt * Dd;
  float2* rope = (float2*)(VgT + (size_t)Bb * Hh * Tt * Dd);  // 1 MB
  bf16* Yg     = xb;    // alias: xb dead by the time attn writes Yg

  hipLaunchKernelGGL(rope_tab, dim3(Tt * 64 / 256), dim3(256), 0, stream, rope);
  hipLaunchKernelGGL(cvt_bf16, dim3((Mm_ * Cc_ / 4) / 256), dim3(256), 0, stream,
                     x, xb, Mm_ * Cc_);
  hipLaunchKernelGGL(transpose_cvt, dim3(N1 / 64, Cc_ / 64), dim3(256), 0, stream,
                     w_qkv, wqkvT, Cc_, N1);
  hipLaunchKernelGGL(transpose_cvt, dim3(Cc_ / 64, Cc_ / 64), dim3(256), 0, stream,
                     w_proj, wprojT, Cc_, Cc_);
  // fused: GEMM + RMSNorm + RoPE + rearrange + V-transpose
  hipLaunchKernelGGL(gemm_qkv_fused, dim3(N1 / 128, Mm_ / 128), dim3(256), 0, stream,
                     xb, wqkvT, qnw, knw, rope, Qg, Kg, VgT);
  hipLaunchKernelGGL(attn, dim3(Bb * Hh, Tt / 64), dim3(256), 0, stream,
                     Qg, Kg, VgT, Yg);
  // proj GEMM: 256x128 tile, 16x16 = 256 wg = exactly 1 round
  hipLaunchKernelGGL(gemm256<float>, dim3(Cc_ / 128, Mm_ / 256), dim3(512), 0, stream,
                     Yg, wprojT, out, Cc_, Cc_);
}